// Round 13
// baseline (252.070 us; speedup 1.0000x reference)
//
#include <hip/hip_runtime.h>
#include <stdint.h>

#define SW 1024
#define NB 512                   // 512 bands x 2 rows
#define N_HITS (1 << 24)
#define B1 1024                  // blocks for count/scatter
#define HPB (N_HITS / B1)        // 16384 hits per block
#define RND (HPB / 1024)         // 16 rounds (256 thr * 4) for k_count
#define SB 4096                  // hits per scatter sub-batch
#define SBF4 (SB / 4)            // 1024 float4 per sub-batch
#define NSB (HPB / SB)           // 4 sub-batches
#define CHUNK 8192               // hits per accumulation chunk
#define MAXCH (NB + N_HITS / CHUNK)   // 512 + 2048 = 2560
#define HISTW 2048               // 2 rows x 1024 cols = 8 KB

// ws layout (u32 words): split pos16/val32 arrays -> 123.8 MB total
// (was 148.9; proven budget 150.9 MB from round 2).
#define OFS_CB    0u                                 // B1*NB counts->bases
#define OFS_TOTAL (OFS_CB + (uint32_t)B1 * NB)       // 524288
#define OFS_BOFF  (OFS_TOTAL + NB)                   // 524800
#define OFS_CBASE (OFS_BOFF + NB + 1)                // 525313
#define OFS_POS   525828u                            // u16 array, 16B-aligned
#define PAIR_CAP  ((uint32_t)N_HITS + 4096u)         // + 8-align slack per band
#define OFS_VAL   (OFS_POS + PAIR_CAP / 2u)          // 8916484 (16B-aligned)
#define OFS_PART  (OFS_VAL + PAIR_CAP)               // 25697796
#define WS_WORDS  (OFS_PART + (uint32_t)MAXCH * HISTW)
#define WS_BYTES  ((size_t)WS_WORDS * 4u)            // 123,762,704 B

#define INV_D 0.005859375f       // 6/1024, exact

typedef float fx4 __attribute__((ext_vector_type(4)));

__device__ __forceinline__ float4 ntload(const float4* p) {
    fx4 v = __builtin_nontemporal_load((const fx4*)p);
    return make_float4(v.x, v.y, v.z, v.w);
}

__device__ __forceinline__ uint32_t pix_of(float x, float y) {
    float fx = floorf((x + 3.0f) / INV_D);
    float fy = floorf((y + 3.0f) / INV_D);
    if (fx >= 0.0f && fx < 1024.0f && fy >= 0.0f && fy < 1024.0f) {
        return ((uint32_t)(int)fy << 10) | (uint32_t)(int)fx;
    }
    return 0xFFFFFFFFu;
}

// ---- pass 1a: per-(block,band) counts from y only ----------------------
__global__ __launch_bounds__(256) void k_count(const float4* __restrict__ y4,
                                               uint32_t* __restrict__ cnt) {
    __shared__ uint32_t lcnt[4 * NB];   // per-wave counters (8 KB)
    int tid = threadIdx.x, b = blockIdx.x;
    int wave = tid >> 6;
#pragma unroll
    for (int q = 0; q < 8; ++q) lcnt[tid + q * 256] = 0;
    __syncthreads();
    int base4 = b * (HPB / 4);
#pragma unroll
    for (int r = 0; r < RND; ++r) {
        float4 yv = ntload(&y4[base4 + r * 256 + tid]);
        float ys[4] = {yv.x, yv.y, yv.z, yv.w};
#pragma unroll
        for (int j = 0; j < 4; ++j) {
            float fy = floorf((ys[j] + 3.0f) / INV_D);
            if (fy >= 0.0f && fy < 1024.0f) {
                atomicAdd(&lcnt[wave * NB + ((int)fy >> 1)], 1u);
            }
        }
    }
    __syncthreads();
#pragma unroll
    for (int q = 0; q < 2; ++q) {
        int t = tid + q * 256;
        cnt[b * NB + t] = lcnt[t] + lcnt[NB + t] + lcnt[2 * NB + t] + lcnt[3 * NB + t];
    }
}

// ---- pass 1b: per-band exclusive scan over blocks (IN PLACE) -----------
__global__ __launch_bounds__(256) void k_scan_blocks(uint32_t* __restrict__ cb,
                                                     uint32_t* __restrict__ total) {
    __shared__ uint32_t s[256];
    __shared__ uint32_t carry;
    int t = blockIdx.x, tid = threadIdx.x;
    if (tid == 0) carry = 0;
    __syncthreads();
    for (int r = 0; r < B1 / 256; ++r) {
        int b = r * 256 + tid;
        uint32_t v = cb[b * NB + t];
        s[tid] = v;
        __syncthreads();
        for (int off = 1; off < 256; off <<= 1) {
            uint32_t add = (tid >= off) ? s[tid - off] : 0u;
            __syncthreads();
            s[tid] += add;
            __syncthreads();
        }
        uint32_t incl = s[tid];
        uint32_t c = carry;
        cb[b * NB + t] = c + incl - v;          // exclusive base, in place
        __syncthreads();
        if (tid == 255) carry = c + incl;
        __syncthreads();
    }
    if (tid == 0) total[t] = carry;
}

// ---- pass 1b2: band offsets (8-pair aligned starts) + chunk bases ------
__global__ __launch_bounds__(64) void k_scan_bands(const uint32_t* __restrict__ total,
                                                   uint32_t* __restrict__ boff,
                                                   uint32_t* __restrict__ cbase) {
    if (threadIdx.x == 0 && blockIdx.x == 0) {
        uint32_t acc = 0, cacc = 0;
        for (int i = 0; i < NB; ++i) {
            boff[i] = acc;
            cbase[i] = cacc;
            uint32_t v = total[i];
            acc += v;
            acc = (acc + 7u) & ~7u;          // 8-pair alignment (16B pos / 32B val)
            uint32_t cc = (v + CHUNK - 1) / CHUNK;
            cacc += (cc == 0) ? 1u : cc;
        }
        boff[NB] = acc;
        cbase[NB] = cacc;
    }
}

// ---- pass 1c: LDS counting-sort scatter (split pos16/val32 output) -----
__global__ __launch_bounds__(512) void k_scatter(const float4* __restrict__ x4,
                                                 const float4* __restrict__ y4,
                                                 const float4* __restrict__ v4,
                                                 const uint32_t* __restrict__ base,
                                                 const uint32_t* __restrict__ boff,
                                                 unsigned short* __restrict__ gpos,
                                                 uint32_t* __restrict__ gval) {
    __shared__ uint32_t bh[NB];        // 2 KB
    __shared__ uint32_t lstart[NB];    // 2 KB
    __shared__ uint32_t lcur[NB];      // 2 KB
    __shared__ uint32_t gcur[NB];      // 2 KB
    __shared__ uint32_t wsum[8];
    __shared__ uint32_t spacked[SB];   // 16 KB (pk = yi<<10|xi)
    __shared__ uint32_t sval[SB];      // 16 KB
    __shared__ uint32_t s_nsb;

    int tid = threadIdx.x, b = blockIdx.x;
    int lane = tid & 63, wid = tid >> 6;
    gcur[tid] = boff[tid] + base[b * NB + tid];

    for (int sb = 0; sb < NSB; ++sb) {
        bh[tid] = 0;
        __syncthreads();

        int i0 = b * (HPB / 4) + sb * SBF4 + tid;
        int i1 = i0 + 512;
        float4 xa = ntload(&x4[i0]), xb = ntload(&x4[i1]);
        float4 ya = ntload(&y4[i0]), yb = ntload(&y4[i1]);
        float4 va = ntload(&v4[i0]), vb = ntload(&v4[i1]);
        float xs[8] = {xa.x, xa.y, xa.z, xa.w, xb.x, xb.y, xb.z, xb.w};
        float ys[8] = {ya.x, ya.y, ya.z, ya.w, yb.x, yb.y, yb.z, yb.w};
        float vs[8] = {va.x, va.y, va.z, va.w, vb.x, vb.y, vb.z, vb.w};
        uint32_t pk[8];
        bool ok[8];
#pragma unroll
        for (int j = 0; j < 8; ++j) {
            float fy = floorf((ys[j] + 3.0f) / INV_D);
            ok[j] = (fy >= 0.0f && fy < 1024.0f);
            uint32_t yi = ok[j] ? (uint32_t)(int)fy : 0u;
            float fx = floorf((xs[j] + 3.0f) / INV_D);
            bool xok = (fx >= 0.0f && fx < 1024.0f);
            pk[j] = (yi << 10) | (xok ? (uint32_t)(int)fx : 0u);
            if (!xok) vs[j] = 0.0f;
            if (ok[j]) atomicAdd(&bh[yi >> 1], 1u);
        }
        __syncthreads();

        // scan of bh: per-wave shuffle scan + 8-wave combine (3 barriers)
        uint32_t v = bh[tid];
        uint32_t inc = v;
#pragma unroll
        for (int off = 1; off < 64; off <<= 1) {
            uint32_t n = __shfl_up(inc, off, 64);
            if (lane >= off) inc += n;
        }
        if (lane == 63) wsum[wid] = inc;
        __syncthreads();
        if (tid == 0) {
            uint32_t a = 0;
#pragma unroll
            for (int w2 = 0; w2 < 8; ++w2) { uint32_t t2 = wsum[w2]; wsum[w2] = a; a += t2; }
            s_nsb = a;
        }
        __syncthreads();
        uint32_t excl = wsum[wid] + inc - v;
        lstart[tid] = excl;
        lcur[tid] = excl;
        __syncthreads();

        // place into LDS sorted buffers (band = pk >> 11)
#pragma unroll
        for (int j = 0; j < 8; ++j) {
            if (ok[j]) {
                uint32_t s = atomicAdd(&lcur[pk[j] >> 11], 1u);
                spacked[s] = pk[j];
                sval[s] = __float_as_uint(vs[j]);
            }
        }
        __syncthreads();

        // coalesced copy-out: consecutive i -> consecutive global addrs
        uint32_t nsb = s_nsb;
        for (uint32_t i = (uint32_t)tid; i < nsb; i += 512) {
            uint32_t q = spacked[i];
            uint32_t t = q >> 11;
            uint32_t idx = gcur[t] + (i - lstart[t]);
            gpos[idx] = (unsigned short)(q & 2047u);
            gval[idx] = sval[i];
        }
        __syncthreads();
        gcur[tid] += bh[tid];
        __syncthreads();
    }
}

// ---- pass 2: per-chunk LDS band histogram (2048 f32, 8 KB) -------------
__global__ __launch_bounds__(512) void k_accum(const unsigned short* __restrict__ gpos,
                                               const uint32_t* __restrict__ gval,
                                               const uint32_t* __restrict__ boff,
                                               const uint32_t* __restrict__ total,
                                               const uint32_t* __restrict__ cbase,
                                               float* __restrict__ partials) {
    __shared__ float hist[HISTW];
    int c = blockIdx.x, tid = threadIdx.x;
    uint32_t nch = cbase[NB];
    if ((uint32_t)c >= nch) return;
    int lo = 0, hi = NB - 1;
    while (lo < hi) {
        int mid = (lo + hi + 1) >> 1;
        if (cbase[mid] <= (uint32_t)c) lo = mid; else hi = mid - 1;
    }
    int t = lo;
    uint32_t k = (uint32_t)c - cbase[t];
    uint32_t st = boff[t] + k * (uint32_t)CHUNK;       // multiple of 8
    uint32_t en = boff[t] + total[t];
    uint32_t en2 = st + (uint32_t)CHUNK;
    if (en2 < en) en = en2;
    for (int i = tid; i < HISTW; i += 512) hist[i] = 0.0f;
    __syncthreads();
    uint32_t npairs = (en > st) ? (en - st) : 0u;
    uint32_t nv = npairs >> 2;                          // 4 pairs per round
    const uint2* p2 = (const uint2*)(gpos + st);        // 4 x u16
    const uint4* v4p = (const uint4*)(gval + st);       // 4 x u32
    for (uint32_t i = (uint32_t)tid; i < nv; i += 512u) {
        uint2 pp = p2[i];
        uint4 vv = v4p[i];
        atomicAdd(&hist[pp.x & 2047u], __uint_as_float(vv.x));
        atomicAdd(&hist[(pp.x >> 16) & 2047u], __uint_as_float(vv.y));
        atomicAdd(&hist[pp.y & 2047u], __uint_as_float(vv.z));
        atomicAdd(&hist[(pp.y >> 16) & 2047u], __uint_as_float(vv.w));
    }
    uint32_t ti = st + (nv << 2) + (uint32_t)tid;       // <=3 tail entries
    if (ti < en) {
        atomicAdd(&hist[(uint32_t)gpos[ti] & 2047u], __uint_as_float(gval[ti]));
    }
    __syncthreads();
    float4* dst = (float4*)(partials + (size_t)c * HISTW);
    const float4* src = (const float4*)hist;
    for (int i2 = tid; i2 < HISTW / 4; i2 += 512) dst[i2] = src[i2];
}

// ---- pass 3: reduce partials, write final image (every pixel once) -----
__global__ __launch_bounds__(256) void k_reduce(const float* __restrict__ partials,
                                                const uint32_t* __restrict__ cbase,
                                                float* __restrict__ out) {
    int t = blockIdx.x, tid = threadIdx.x;
    uint32_t c0 = cbase[t], c1 = cbase[t + 1];
    float4* o4 = (float4*)(out + (size_t)t * HISTW);
    for (int i = tid; i < HISTW / 4; i += 256) {
        float4 s = make_float4(0.f, 0.f, 0.f, 0.f);
        for (uint32_t c = c0; c < c1; ++c) {
            float4 p = ((const float4*)(partials + (size_t)c * HISTW))[i];
            s.x += p.x; s.y += p.y; s.z += p.z; s.w += p.w;
        }
        o4[i] = s;
    }
}

// ---- fallback: direct-atomic version (known-correct) -------------------
__global__ __launch_bounds__(256) void k_naive(const float4* __restrict__ x4,
                                               const float4* __restrict__ y4,
                                               const float4* __restrict__ v4,
                                               float* __restrict__ out,
                                               int n_chunks) {
    int stride = gridDim.x * blockDim.x;
    for (int i = blockIdx.x * blockDim.x + threadIdx.x; i < n_chunks; i += stride) {
        float4 xv = x4[i];
        float4 yv = y4[i];
        float4 vv = v4[i];
        float xs[4] = {xv.x, xv.y, xv.z, xv.w};
        float ys[4] = {yv.x, yv.y, yv.z, yv.w};
        float vs[4] = {vv.x, vv.y, vv.z, vv.w};
#pragma unroll
        for (int j = 0; j < 4; ++j) {
            uint32_t p = pix_of(xs[j], ys[j]);
            if (p != 0xFFFFFFFFu) atomicAdd(&out[(p >> 10) * SW + (p & 1023u)], vs[j]);
        }
    }
}

extern "C" void kernel_launch(void* const* d_in, const int* in_sizes, int n_in,
                              void* d_out, int out_size, void* d_ws, size_t ws_size,
                              hipStream_t stream) {
    const float* x = (const float*)d_in[0];
    const float* y = (const float*)d_in[1];
    const float* v = (const float*)d_in[2];
    float* out = (float*)d_out;
    int n = in_sizes[0];

    if (n == N_HITS && ws_size >= WS_BYTES) {
        uint32_t* w = (uint32_t*)d_ws;
        uint32_t* cb    = w + OFS_CB;      // counts, then in-place bases
        uint32_t* total = w + OFS_TOTAL;
        uint32_t* boff  = w + OFS_BOFF;
        uint32_t* cbase = w + OFS_CBASE;
        unsigned short* gpos = (unsigned short*)(w + OFS_POS);
        uint32_t* gval  = w + OFS_VAL;
        float*    parts = (float*)(w + OFS_PART);

        k_count<<<B1, 256, 0, stream>>>((const float4*)y, cb);
        k_scan_blocks<<<NB, 256, 0, stream>>>(cb, total);
        k_scan_bands<<<1, 64, 0, stream>>>(total, boff, cbase);
        k_scatter<<<B1, 512, 0, stream>>>((const float4*)x, (const float4*)y,
                                          (const float4*)v, cb, boff, gpos, gval);
        k_accum<<<MAXCH, 512, 0, stream>>>(gpos, gval, boff, total, cbase, parts);
        k_reduce<<<NB, 256, 0, stream>>>(parts, cbase, out);
    } else {
        (void)hipMemsetAsync(out, 0, (size_t)out_size * sizeof(float), stream);
        k_naive<<<4096, 256, 0, stream>>>((const float4*)x, (const float4*)y,
                                          (const float4*)v, out, n / 4);
    }
}

// Round 14
// 243.203 us; speedup vs baseline: 1.0365x; 1.0365x over previous
//
#include <hip/hip_runtime.h>
#include <stdint.h>

#define SW 1024
#define NB 512                   // 512 bands x 2 rows
#define N_HITS (1 << 24)
#define B1 1024                  // blocks for count/scatter
#define HPB (N_HITS / B1)        // 16384 hits per block
#define RND (HPB / 1024)         // 16 rounds (256 thr * 4) for k_count
#define SB 8192                  // hits per scatter sub-batch (64 KB sort buf)
#define SBF4 (SB / 4)            // 2048 float4 per sub-batch
#define NSB (HPB / SB)           // 2 sub-batches
#define CHUNK 14336              // hits per accumulation chunk (even)
#define MAXCH 1683               // 512 + ceil-sum bound (<= 512 + 1171)
#define HISTW 2048               // 2 rows x 1024 cols = 8 KB

// ws layout (u32 words): 150.12 MB <= 150.99 MB proven available (round 2).
#define OFS_CB    0u                                 // B1*NB counts->bases
#define OFS_TOTAL (OFS_CB + (uint32_t)B1 * NB)       // 524288
#define OFS_BOFF  (OFS_TOTAL + NB)                   // 524800
#define OFS_CBASE (OFS_BOFF + NB + 1)                // 525313
#define OFS_PAIRS 525828u                            // mult of 4 -> 16B aligned
#define PAIR_CAP  ((uint32_t)N_HITS + 1024u)         // + 2-pair align slack/band
#define OFS_PART  (OFS_PAIRS + 2u * PAIR_CAP)        // 34082308
#define WS_WORDS  (OFS_PART + (uint32_t)MAXCH * HISTW)
#define WS_BYTES  ((size_t)WS_WORDS * 4u)            // 150,116,368 B

#define INV_D 0.005859375f       // 6/1024, exact

typedef float fx4 __attribute__((ext_vector_type(4)));
typedef unsigned int ux4 __attribute__((ext_vector_type(4)));

__device__ __forceinline__ float4 ntload(const float4* p) {
    fx4 v = __builtin_nontemporal_load((const fx4*)p);
    return make_float4(v.x, v.y, v.z, v.w);
}
__device__ __forceinline__ uint4 ntload_u4(const uint4* p) {
    ux4 v = __builtin_nontemporal_load((const ux4*)p);
    return make_uint4(v.x, v.y, v.z, v.w);
}

__device__ __forceinline__ uint32_t pix_of(float x, float y) {
    float fx = floorf((x + 3.0f) / INV_D);
    float fy = floorf((y + 3.0f) / INV_D);
    if (fx >= 0.0f && fx < 1024.0f && fy >= 0.0f && fy < 1024.0f) {
        return ((uint32_t)(int)fy << 10) | (uint32_t)(int)fx;
    }
    return 0xFFFFFFFFu;
}

// ---- pass 1a: per-(block,band) counts from y only ----------------------
__global__ __launch_bounds__(256) void k_count(const float4* __restrict__ y4,
                                               uint32_t* __restrict__ cnt) {
    __shared__ uint32_t lcnt[4 * NB];   // per-wave counters (8 KB)
    int tid = threadIdx.x, b = blockIdx.x;
    int wave = tid >> 6;
#pragma unroll
    for (int q = 0; q < 8; ++q) lcnt[tid + q * 256] = 0;
    __syncthreads();
    int base4 = b * (HPB / 4);
#pragma unroll
    for (int r = 0; r < RND; ++r) {
        float4 yv = ntload(&y4[base4 + r * 256 + tid]);
        float ys[4] = {yv.x, yv.y, yv.z, yv.w};
#pragma unroll
        for (int j = 0; j < 4; ++j) {
            float fy = floorf((ys[j] + 3.0f) / INV_D);
            if (fy >= 0.0f && fy < 1024.0f) {
                atomicAdd(&lcnt[wave * NB + ((int)fy >> 1)], 1u);
            }
        }
    }
    __syncthreads();
#pragma unroll
    for (int q = 0; q < 2; ++q) {
        int t = tid + q * 256;
        cnt[b * NB + t] = lcnt[t] + lcnt[NB + t] + lcnt[2 * NB + t] + lcnt[3 * NB + t];
    }
}

// ---- pass 1b: per-band exclusive scan over blocks (IN PLACE) -----------
__global__ __launch_bounds__(256) void k_scan_blocks(uint32_t* __restrict__ cb,
                                                     uint32_t* __restrict__ total) {
    __shared__ uint32_t s[256];
    __shared__ uint32_t carry;
    int t = blockIdx.x, tid = threadIdx.x;
    if (tid == 0) carry = 0;
    __syncthreads();
    for (int r = 0; r < B1 / 256; ++r) {
        int b = r * 256 + tid;
        uint32_t v = cb[b * NB + t];
        s[tid] = v;
        __syncthreads();
        for (int off = 1; off < 256; off <<= 1) {
            uint32_t add = (tid >= off) ? s[tid - off] : 0u;
            __syncthreads();
            s[tid] += add;
            __syncthreads();
        }
        uint32_t incl = s[tid];
        uint32_t c = carry;
        cb[b * NB + t] = c + incl - v;          // exclusive base, in place
        __syncthreads();
        if (tid == 255) carry = c + incl;
        __syncthreads();
    }
    if (tid == 0) total[t] = carry;
}

// ---- pass 1b2: band offsets (2-pair aligned starts) + chunk bases ------
__global__ __launch_bounds__(64) void k_scan_bands(const uint32_t* __restrict__ total,
                                                   uint32_t* __restrict__ boff,
                                                   uint32_t* __restrict__ cbase) {
    if (threadIdx.x == 0 && blockIdx.x == 0) {
        uint32_t acc = 0, cacc = 0;
        for (int i = 0; i < NB; ++i) {
            boff[i] = acc;
            cbase[i] = cacc;
            uint32_t v = total[i];
            acc += v;
            acc = (acc + 1u) & ~1u;          // 16B-aligned band starts
            uint32_t cc = (v + CHUNK - 1) / CHUNK;
            cacc += (cc == 0) ? 1u : cc;
        }
        boff[NB] = acc;
        cbase[NB] = cacc;
    }
}

// ---- pass 1c: LDS counting-sort scatter, SB=8192 (128B avg band runs) --
__global__ __launch_bounds__(512) void k_scatter(const float4* __restrict__ x4,
                                                 const float4* __restrict__ y4,
                                                 const float4* __restrict__ v4,
                                                 const uint32_t* __restrict__ base,
                                                 const uint32_t* __restrict__ boff,
                                                 uint2* __restrict__ pairs) {
    __shared__ uint32_t bh[NB];        // 2 KB
    __shared__ uint32_t lstart[NB];    // 2 KB
    __shared__ uint32_t lcur[NB];      // 2 KB
    __shared__ uint32_t gcur[NB];      // 2 KB
    __shared__ uint32_t wsum[8];
    __shared__ uint2 sorted[SB];       // 64 KB
    __shared__ uint32_t s_nsb;

    int tid = threadIdx.x, b = blockIdx.x;
    int lane = tid & 63, wid = tid >> 6;
    gcur[tid] = boff[tid] + base[b * NB + tid];

    for (int sb = 0; sb < NSB; ++sb) {
        bh[tid] = 0;
        __syncthreads();

        int i0 = b * (HPB / 4) + sb * SBF4 + tid;
        float4 xr[4], yr[4], vr[4];
#pragma unroll
        for (int q = 0; q < 4; ++q) {
            xr[q] = ntload(&x4[i0 + q * 512]);
            yr[q] = ntload(&y4[i0 + q * 512]);
            vr[q] = ntload(&v4[i0 + q * 512]);
        }
        float xs[16], ys[16], vs[16];
#pragma unroll
        for (int q = 0; q < 4; ++q) {
            xs[q*4+0]=xr[q].x; xs[q*4+1]=xr[q].y; xs[q*4+2]=xr[q].z; xs[q*4+3]=xr[q].w;
            ys[q*4+0]=yr[q].x; ys[q*4+1]=yr[q].y; ys[q*4+2]=yr[q].z; ys[q*4+3]=yr[q].w;
            vs[q*4+0]=vr[q].x; vs[q*4+1]=vr[q].y; vs[q*4+2]=vr[q].z; vs[q*4+3]=vr[q].w;
        }
        uint32_t pk[16];
        bool ok[16];
#pragma unroll
        for (int j = 0; j < 16; ++j) {
            float fy = floorf((ys[j] + 3.0f) / INV_D);
            ok[j] = (fy >= 0.0f && fy < 1024.0f);
            uint32_t yi = ok[j] ? (uint32_t)(int)fy : 0u;
            float fx = floorf((xs[j] + 3.0f) / INV_D);
            bool xok = (fx >= 0.0f && fx < 1024.0f);
            pk[j] = (yi << 10) | (xok ? (uint32_t)(int)fx : 0u);
            if (!xok) vs[j] = 0.0f;
            if (ok[j]) atomicAdd(&bh[yi >> 1], 1u);
        }
        __syncthreads();

        // scan of bh: per-wave shuffle scan + 8-wave combine (3 barriers)
        uint32_t v = bh[tid];
        uint32_t inc = v;
#pragma unroll
        for (int off = 1; off < 64; off <<= 1) {
            uint32_t n = __shfl_up(inc, off, 64);
            if (lane >= off) inc += n;
        }
        if (lane == 63) wsum[wid] = inc;
        __syncthreads();
        if (tid == 0) {
            uint32_t a = 0;
#pragma unroll
            for (int w2 = 0; w2 < 8; ++w2) { uint32_t t2 = wsum[w2]; wsum[w2] = a; a += t2; }
            s_nsb = a;
        }
        __syncthreads();
        uint32_t excl = wsum[wid] + inc - v;
        lstart[tid] = excl;
        lcur[tid] = excl;
        __syncthreads();

        // place into LDS sorted buffer (band = pk >> 11)
#pragma unroll
        for (int j = 0; j < 16; ++j) {
            if (ok[j]) {
                uint32_t s = atomicAdd(&lcur[pk[j] >> 11], 1u);
                sorted[s] = make_uint2(pk[j], __float_as_uint(vs[j]));
            }
        }
        __syncthreads();

        // coalesced copy-out: consecutive i -> consecutive global addrs;
        // avg run = 16 pairs = 128 B (2 full lines) -> L2 write-combines.
        uint32_t nsb = s_nsb;
        for (uint32_t i = (uint32_t)tid; i < nsb; i += 512) {
            uint2 pr = sorted[i];
            uint32_t t = pr.x >> 11;
            pairs[gcur[t] + (i - lstart[t])] = pr;
        }
        __syncthreads();
        gcur[tid] += bh[tid];
        __syncthreads();
    }
}

// ---- pass 2: per-chunk LDS band histogram (2048 f32, 8 KB) -------------
#define ACC1(a) \
    atomicAdd(&hist[(((a).x >> 10) & 1u) * 1024 + ((a).x & 1023u)], __uint_as_float((a).y)); \
    atomicAdd(&hist[(((a).z >> 10) & 1u) * 1024 + ((a).z & 1023u)], __uint_as_float((a).w));

__global__ __launch_bounds__(512) void k_accum(const uint2* __restrict__ pairs,
                                               const uint32_t* __restrict__ boff,
                                               const uint32_t* __restrict__ total,
                                               const uint32_t* __restrict__ cbase,
                                               float* __restrict__ partials) {
    __shared__ float hist[HISTW];
    int c = blockIdx.x, tid = threadIdx.x;
    uint32_t nch = cbase[NB];
    if ((uint32_t)c >= nch) return;
    int lo = 0, hi = NB - 1;
    while (lo < hi) {
        int mid = (lo + hi + 1) >> 1;
        if (cbase[mid] <= (uint32_t)c) lo = mid; else hi = mid - 1;
    }
    int t = lo;
    uint32_t k = (uint32_t)c - cbase[t];
    uint32_t st = boff[t] + k * (uint32_t)CHUNK;       // even
    uint32_t en = boff[t] + total[t];
    uint32_t en2 = st + (uint32_t)CHUNK;
    if (en2 < en) en = en2;
    for (int i = tid; i < HISTW; i += 512) hist[i] = 0.0f;
    __syncthreads();
    uint32_t npairs = (en > st) ? (en - st) : 0u;
    uint32_t nv = npairs >> 1;                          // uint4 = 2 pairs
    const uint4* p4 = (const uint4*)(pairs + st);
    for (uint32_t i = (uint32_t)tid; i < nv; i += 512u) {
        uint4 a = ntload_u4(&p4[i]);                    // nt: streaming read
        ACC1(a)
    }
    if ((npairs & 1u) && tid == 0) {
        uint2 pr = pairs[en - 1];
        atomicAdd(&hist[((pr.x >> 10) & 1u) * 1024 + (pr.x & 1023u)],
                  __uint_as_float(pr.y));
    }
    __syncthreads();
    float4* dst = (float4*)(partials + (size_t)c * HISTW);
    const float4* src = (const float4*)hist;
    for (int i2 = tid; i2 < HISTW / 4; i2 += 512) dst[i2] = src[i2];
}

// ---- pass 3: reduce partials, write final image (every pixel once) -----
__global__ __launch_bounds__(256) void k_reduce(const float* __restrict__ partials,
                                                const uint32_t* __restrict__ cbase,
                                                float* __restrict__ out) {
    int t = blockIdx.x, tid = threadIdx.x;
    uint32_t c0 = cbase[t], c1 = cbase[t + 1];
    float4* o4 = (float4*)(out + (size_t)t * HISTW);
    for (int i = tid; i < HISTW / 4; i += 256) {
        float4 s = make_float4(0.f, 0.f, 0.f, 0.f);
        for (uint32_t c = c0; c < c1; ++c) {
            float4 p = ((const float4*)(partials + (size_t)c * HISTW))[i];
            s.x += p.x; s.y += p.y; s.z += p.z; s.w += p.w;
        }
        o4[i] = s;
    }
}

// ---- fallback: direct-atomic version (known-correct) -------------------
__global__ __launch_bounds__(256) void k_naive(const float4* __restrict__ x4,
                                               const float4* __restrict__ y4,
                                               const float4* __restrict__ v4,
                                               float* __restrict__ out,
                                               int n_chunks) {
    int stride = gridDim.x * blockDim.x;
    for (int i = blockIdx.x * blockDim.x + threadIdx.x; i < n_chunks; i += stride) {
        float4 xv = x4[i];
        float4 yv = y4[i];
        float4 vv = v4[i];
        float xs[4] = {xv.x, xv.y, xv.z, xv.w};
        float ys[4] = {yv.x, yv.y, yv.z, yv.w};
        float vs[4] = {vv.x, vv.y, vv.z, vv.w};
#pragma unroll
        for (int j = 0; j < 4; ++j) {
            uint32_t p = pix_of(xs[j], ys[j]);
            if (p != 0xFFFFFFFFu) atomicAdd(&out[(p >> 10) * SW + (p & 1023u)], vs[j]);
        }
    }
}

extern "C" void kernel_launch(void* const* d_in, const int* in_sizes, int n_in,
                              void* d_out, int out_size, void* d_ws, size_t ws_size,
                              hipStream_t stream) {
    const float* x = (const float*)d_in[0];
    const float* y = (const float*)d_in[1];
    const float* v = (const float*)d_in[2];
    float* out = (float*)d_out;
    int n = in_sizes[0];

    if (n == N_HITS && ws_size >= WS_BYTES) {
        uint32_t* w = (uint32_t*)d_ws;
        uint32_t* cb    = w + OFS_CB;      // counts, then in-place bases
        uint32_t* total = w + OFS_TOTAL;
        uint32_t* boff  = w + OFS_BOFF;
        uint32_t* cbase = w + OFS_CBASE;
        uint2*    pairs = (uint2*)(w + OFS_PAIRS);
        float*    parts = (float*)(w + OFS_PART);

        k_count<<<B1, 256, 0, stream>>>((const float4*)y, cb);
        k_scan_blocks<<<NB, 256, 0, stream>>>(cb, total);
        k_scan_bands<<<1, 64, 0, stream>>>(total, boff, cbase);
        k_scatter<<<B1, 512, 0, stream>>>((const float4*)x, (const float4*)y,
                                          (const float4*)v, cb, boff, pairs);
        k_accum<<<MAXCH, 512, 0, stream>>>(pairs, boff, total, cbase, parts);
        k_reduce<<<NB, 256, 0, stream>>>(parts, cbase, out);
    } else {
        (void)hipMemsetAsync(out, 0, (size_t)out_size * sizeof(float), stream);
        k_naive<<<4096, 256, 0, stream>>>((const float4*)x, (const float4*)y,
                                          (const float4*)v, out, n / 4);
    }
}